// Round 10
// baseline (238.913 us; speedup 1.0000x reference)
//
#include <hip/hip_runtime.h>
#include <math.h>

#define DIN 48
#define DOUT 48
#define NPB 128              // nodes per bucket (d_local = d & 127)
#define NB_MAX 800           // >= ceil(100000/128)=782
#define BIN_BLOCKS 512
#define EPB_MAX 3136         // per-block edge window (>= ceil(1.6M/512)=3125)
#define INIT_KEY 0x007FFFFFu // fkey(-inf)
#define NT_BLOCK 256
#define NT_PAD 49            // odd stride: conflict-free LDS transpose

__device__ __forceinline__ float funkey(unsigned k) {
  unsigned b = (k & 0x80000000u) ? (k & 0x7FFFFFFFu) : ~k;
  return __uint_as_float(b);
}
// key from raw bf16 bits (order-isomorphic to the float key)
__device__ __forceinline__ unsigned bfkey(unsigned u16) {
  unsigned b = u16 << 16;
  return (b & 0x80000000u) ? ~b : (b | 0x80000000u);
}
// float -> bf16 bits, round-to-nearest-even
__device__ __forceinline__ unsigned short f2bf(float f) {
  unsigned u = __float_as_uint(f);
  return (unsigned short)((u + 0x7fffu + ((u >> 16) & 1u)) >> 16);
}

// ---------------- prep: Wb = phi_w - theta_w ----------------
__global__ __launch_bounds__(256) void prep(
    const float* __restrict__ tw, const float* __restrict__ pw,
    float* __restrict__ wb) {
  int i = blockIdx.x * 256 + threadIdx.x;
  if (i < DIN * DOUT) wb[i] = pw[i] - tw[i];
}

// ---------------- per-node linear transforms ----------------
// A[v] = h[v]@theta_w^T + theta_b  (fp32 -> d_out; bucket_max epilogue adds it)
// B[v] = h[v]@Wb^T + phi_b         (bf16 -> workspace; halves gather traffic)
// 256 nodes/block, 1 thread/node, 4 independent FMA chains (round-7 lesson:
// single chain is latency-bound); VGPR ~88 (round-9 lesson: 2-thr/node split
// pushed VGPR to 116 and capped occupancy).
__global__ __launch_bounds__(NT_BLOCK) void node_transform(
    const float* __restrict__ h, const float* __restrict__ tw,
    const float* __restrict__ tb, const float* __restrict__ wb,
    const float* __restrict__ pb, float* __restrict__ A,
    unsigned short* __restrict__ Bh, int n_nodes) {
  __shared__ float sm[NT_BLOCK * NT_PAD];  // 50.2 KB
  int t = threadIdx.x;
  int v0 = blockIdx.x * NT_BLOCK;
  int v = v0 + t;
  float hr[DIN];
  if (v < n_nodes) {
    const float4* h4 = reinterpret_cast<const float4*>(h + (size_t)v * DIN);
#pragma unroll
    for (int i = 0; i < DIN / 4; ++i) {
      float4 x = h4[i];
      hr[4 * i + 0] = x.x; hr[4 * i + 1] = x.y;
      hr[4 * i + 2] = x.z; hr[4 * i + 3] = x.w;
    }
  } else {
#pragma unroll
    for (int i = 0; i < DIN; ++i) hr[i] = 0.f;
  }
  float* myrow = &sm[t * NT_PAD];

  // ---- pass 1: A = h@theta^T + tb ----
  for (int f = 0; f < DOUT; f += 4) {
    const float* __restrict__ w0 = tw + (f + 0) * DIN;  // wave-uniform -> s_load
    const float* __restrict__ w1 = tw + (f + 1) * DIN;
    const float* __restrict__ w2 = tw + (f + 2) * DIN;
    const float* __restrict__ w3 = tw + (f + 3) * DIN;
    float a0 = tb[f + 0], a1 = tb[f + 1], a2 = tb[f + 2], a3 = tb[f + 3];
#pragma unroll
    for (int i = 0; i < DIN; ++i) {
      float hv = hr[i];
      a0 = fmaf(hv, w0[i], a0); a1 = fmaf(hv, w1[i], a1);
      a2 = fmaf(hv, w2[i], a2); a3 = fmaf(hv, w3[i], a3);
    }
    myrow[f + 0] = a0; myrow[f + 1] = a1; myrow[f + 2] = a2; myrow[f + 3] = a3;
  }
  __syncthreads();
  {  // coalesced fp32 A store: 3072 float4, 12 per thread
    float* dstp = A + (size_t)v0 * DOUT;
#pragma unroll
    for (int k = 0; k < 12; ++k) {
      int idx = k * NT_BLOCK + t;
      int nn = idx / 12, cc = idx % 12;
      if (v0 + nn < n_nodes) {
        const float* r = &sm[nn * NT_PAD + cc * 4];
        *reinterpret_cast<float4*>(dstp + (size_t)idx * 4) =
            make_float4(r[0], r[1], r[2], r[3]);
      }
    }
  }
  __syncthreads();

  // ---- pass 2: B = h@Wb^T + pb ----
  for (int f = 0; f < DOUT; f += 4) {
    const float* __restrict__ w0 = wb + (f + 0) * DIN;
    const float* __restrict__ w1 = wb + (f + 1) * DIN;
    const float* __restrict__ w2 = wb + (f + 2) * DIN;
    const float* __restrict__ w3 = wb + (f + 3) * DIN;
    float a0 = pb[f + 0], a1 = pb[f + 1], a2 = pb[f + 2], a3 = pb[f + 3];
#pragma unroll
    for (int i = 0; i < DIN; ++i) {
      float hv = hr[i];
      a0 = fmaf(hv, w0[i], a0); a1 = fmaf(hv, w1[i], a1);
      a2 = fmaf(hv, w2[i], a2); a3 = fmaf(hv, w3[i], a3);
    }
    myrow[f + 0] = a0; myrow[f + 1] = a1; myrow[f + 2] = a2; myrow[f + 3] = a3;
  }
  __syncthreads();
  {  // coalesced bf16 B store: 3072 ushort4 (8B), 12 per thread
    unsigned short* dstp = Bh + (size_t)v0 * DOUT;
#pragma unroll
    for (int k = 0; k < 12; ++k) {
      int idx = k * NT_BLOCK + t;
      int nn = idx / 12, cc = idx % 12;
      if (v0 + nn < n_nodes) {
        const float* r = &sm[nn * NT_PAD + cc * 4];
        ushort4 o;
        o.x = f2bf(r[0]); o.y = f2bf(r[1]); o.z = f2bf(r[2]); o.w = f2bf(r[3]);
        *reinterpret_cast<ushort4*>(dstp + (size_t)idx * 4) = o;
      }
    }
  }
}

// ---------------- bin edges: per-block LDS counting sort ----------------
// Deterministic replacement for the staged-flush machinery (rounds 5-9):
// zero global atomics, 3 barriers, exact sizes. Records land bucket-grouped
// in the block's private 12.5 KB window; the scattered stores are temporally
// clustered within one window -> L2 write-combines to full lines.
__global__ __launch_bounds__(256) void bin_edges(
    const int* __restrict__ src, const int* __restrict__ dst,
    unsigned* __restrict__ ebuf, unsigned* __restrict__ soffs,
    int n_edges, int nbucket, int epb) {
  __shared__ unsigned rec[EPB_MAX];          // 12.5 KB
  __shared__ unsigned short rbkt[EPB_MAX];   // 6.3 KB
  __shared__ unsigned cnt[NB_MAX];           // 3.2 KB (counts -> offsets -> cursors)
  __shared__ unsigned part[256];             // 1 KB scan partials
  int t = threadIdx.x, r = blockIdx.x;
  for (int b = t; b < nbucket; b += 256) cnt[b] = 0;
  __syncthreads();

  int start = r * epb;
  int nrec = n_edges - start;
  if (nrec > epb) nrec = epb;
  if (nrec < 0) nrec = 0;

  // pass A: stage + count
  for (int k = t; k < nrec; k += 256) {
    int s = src[start + k], d = dst[start + k];
    int b = d >> 7;  // d / NPB
    rec[k] = ((unsigned)(d & (NPB - 1)) << 17) | (unsigned)s;
    rbkt[k] = (unsigned short)b;
    atomicAdd(&cnt[b], 1u);
  }
  __syncthreads();

  // block-local exclusive scan of cnt[0..nbucket)
  int per = (nbucket + 255) / 256;  // 4
  unsigned local[8];
  unsigned s = 0;
#pragma unroll 4
  for (int i = 0; i < per; ++i) {
    int idx = t * per + i;
    local[i] = (idx < nbucket) ? cnt[idx] : 0u;
    s += local[i];
  }
  part[t] = s;
  __syncthreads();
  for (int off = 1; off < 256; off <<= 1) {
    unsigned v = (t >= off) ? part[t - off] : 0u;
    __syncthreads();
    part[t] += v;
    __syncthreads();
  }
  unsigned run = part[t] - s;  // exclusive prefix of this thread's chunk
  unsigned* orow = soffs + (size_t)r * (nbucket + 1);
#pragma unroll 4
  for (int i = 0; i < per; ++i) {
    int idx = t * per + i;
    if (idx < nbucket) {
      cnt[idx] = run;          // becomes cursor
      orow[idx] = run;         // coalesced offset-row write
      run += local[i];
    }
  }
  if (t == 0) orow[nbucket] = (unsigned)nrec;
  __syncthreads();

  // pass B: place records bucket-grouped into the block's private window
  for (int k = t; k < nrec; k += 256) {
    unsigned p = atomicAdd(&cnt[rbkt[k]], 1u);
    ebuf[(size_t)r * epb + p] = rec[k];
  }
}

// ---------------- per-bucket scatter-max in LDS ----------------
// One block per bucket of 128 nodes. Segment bounds for all 512 regions are
// loaded once (one thread each -> LDS); 42 groups of 12 lanes walk regions
// round-robin reading contiguous mean-4-record segments; bf16 gathers
// (96 B/record); non-returning LDS atomicMax on monotone keys; coalesced
// epilogue adds A (already in d_out).
#define BM_THREADS 512
#define BM_GROUPS 42
__global__ __launch_bounds__(BM_THREADS) void bucket_max(
    const unsigned* __restrict__ ebuf, const unsigned* __restrict__ soffs,
    const unsigned short* __restrict__ Bh, float* __restrict__ out,
    int n_nodes, int nbucket, int epb) {
  __shared__ unsigned keys[NPB * DOUT];   // 24.6 KB
  __shared__ unsigned segs[BIN_BLOCKS];   // 2 KB: (start | end<<16), both < 3136
  int t = threadIdx.x;
  int bkt = blockIdx.x;
#pragma unroll
  for (int i = t; i < NPB * DOUT; i += BM_THREADS) keys[i] = INIT_KEY;
  if (t < BIN_BLOCKS) {
    const unsigned* row = soffs + (size_t)t * (nbucket + 1);
    unsigned a = row[bkt], b = row[bkt + 1];
    segs[t] = a | (b << 16);
  }
  __syncthreads();

  int g = t / 12;
  int c = t % 12;
  if (g < BM_GROUPS) {
    for (int r = g; r < BIN_BLOCKS; r += BM_GROUPS) {
      unsigned se = segs[r];
      unsigned j0 = se & 0xffffu, j1 = se >> 16;
      const unsigned* ep = ebuf + (size_t)r * epb;
      unsigned j = j0;
      for (; j + 1 < j1; j += 2) {  // 2-wide: two gathers in flight
        unsigned v0 = ep[j], v1 = ep[j + 1];
        uint2 b0 = *reinterpret_cast<const uint2*>(Bh + (size_t)(v0 & 0x1FFFF) * DOUT + c * 4);
        uint2 b1 = *reinterpret_cast<const uint2*>(Bh + (size_t)(v1 & 0x1FFFF) * DOUT + c * 4);
        unsigned* k0 = &keys[(v0 >> 17) * DOUT + c * 4];
        unsigned* k1 = &keys[(v1 >> 17) * DOUT + c * 4];
        atomicMax(&k0[0], bfkey(b0.x & 0xffffu)); atomicMax(&k0[1], bfkey(b0.x >> 16));
        atomicMax(&k0[2], bfkey(b0.y & 0xffffu)); atomicMax(&k0[3], bfkey(b0.y >> 16));
        atomicMax(&k1[0], bfkey(b1.x & 0xffffu)); atomicMax(&k1[1], bfkey(b1.x >> 16));
        atomicMax(&k1[2], bfkey(b1.y & 0xffffu)); atomicMax(&k1[3], bfkey(b1.y >> 16));
      }
      if (j < j1) {
        unsigned v0 = ep[j];
        uint2 b0 = *reinterpret_cast<const uint2*>(Bh + (size_t)(v0 & 0x1FFFF) * DOUT + c * 4);
        unsigned* k0 = &keys[(v0 >> 17) * DOUT + c * 4];
        atomicMax(&k0[0], bfkey(b0.x & 0xffffu)); atomicMax(&k0[1], bfkey(b0.x >> 16));
        atomicMax(&k0[2], bfkey(b0.y & 0xffffu)); atomicMax(&k0[3], bfkey(b0.y >> 16));
      }
    }
  }
  __syncthreads();

  // epilogue: out = (untouched) ? 0 : A + decode(key); A already in `out`
  int node0 = bkt * NPB;
  for (int i = t; i < NPB * (DOUT / 4); i += BM_THREADS) {
    int n = i / (DOUT / 4), cc = i % (DOUT / 4);
    int v = node0 + n;
    if (v < n_nodes) {
      unsigned* kp = &keys[n * DOUT + 4 * cc];
      unsigned k0 = kp[0], k1 = kp[1], k2 = kp[2], k3 = kp[3];
      float4* op = reinterpret_cast<float4*>(out + (size_t)v * DOUT + 4 * cc);
      float4 a = *op;
      float4 r;
      r.x = (k0 == INIT_KEY) ? 0.f : a.x + funkey(k0);
      r.y = (k1 == INIT_KEY) ? 0.f : a.y + funkey(k1);
      r.z = (k2 == INIT_KEY) ? 0.f : a.z + funkey(k2);
      r.w = (k3 == INIT_KEY) ? 0.f : a.w + funkey(k3);
      *op = r;
    }
  }
}

extern "C" void kernel_launch(void* const* d_in, const int* in_sizes, int n_in,
                              void* d_out, int out_size, void* d_ws, size_t ws_size,
                              hipStream_t stream) {
  const float* h  = (const float*)d_in[0];
  const float* tw = (const float*)d_in[1];
  const float* tb = (const float*)d_in[2];
  const float* pw = (const float*)d_in[3];
  const float* pb = (const float*)d_in[4];
  const int* src  = (const int*)d_in[5];
  const int* dst  = (const int*)d_in[6];
  int n_nodes = in_sizes[0] / DIN;
  int n_edges = in_sizes[5];
  int nbucket = (n_nodes + NPB - 1) / NPB;             // 782
  int epb = (n_edges + BIN_BLOCKS - 1) / BIN_BLOCKS;   // 3125

  // workspace layout
  unsigned short* Bh = (unsigned short*)d_ws;                        // 9.6 MB
  unsigned* ebuf     = (unsigned*)(Bh + (size_t)n_nodes * DOUT);     // 6.4 MB
  unsigned* soffs    = ebuf + (size_t)BIN_BLOCKS * epb;              // 1.6 MB
  float* wb          = (float*)(soffs + (size_t)BIN_BLOCKS * (nbucket + 1));
  float* A           = (float*)d_out;

  int nt_blocks = (n_nodes + NT_BLOCK - 1) / NT_BLOCK;  // 391
  int nb_prep = (DIN * DOUT + 255) / 256;

  prep<<<nb_prep, 256, 0, stream>>>(tw, pw, wb);
  node_transform<<<nt_blocks, NT_BLOCK, 0, stream>>>(h, tw, tb, wb, pb, A, Bh, n_nodes);
  bin_edges<<<BIN_BLOCKS, 256, 0, stream>>>(src, dst, ebuf, soffs, n_edges, nbucket, epb);
  bucket_max<<<nbucket, BM_THREADS, 0, stream>>>(ebuf, soffs, Bh, A, n_nodes, nbucket, epb);
}

// Round 11
// 165.072 us; speedup vs baseline: 1.4473x; 1.4473x over previous
//
#include <hip/hip_runtime.h>
#include <math.h>

#define DIN 48
#define DOUT 48
#define NPB 128              // nodes per bucket (d_local = d & 127)
#define NB_MAX 800           // >= ceil(100000/128)=782
#define BIN_BLOCKS 512
#define EPB_MAX 3136         // per-block edge window (>= ceil(1.6M/512)=3125)
#define INIT_KEY 0x007FFFFFu // fkey(-inf)

typedef short s16x8 __attribute__((ext_vector_type(8)));   // 8 bf16 (4 VGPRs)
typedef float f32x4v __attribute__((ext_vector_type(4)));  // MFMA acc

__device__ __forceinline__ float funkey(unsigned k) {
  unsigned b = (k & 0x80000000u) ? (k & 0x7FFFFFFFu) : ~k;
  return __uint_as_float(b);
}
// key from raw bf16 bits (order-isomorphic to the float key)
__device__ __forceinline__ unsigned bfkey(unsigned u16) {
  unsigned b = u16 << 16;
  return (b & 0x80000000u) ? ~b : (b | 0x80000000u);
}
// float -> bf16 bits, round-to-nearest-even
__device__ __forceinline__ unsigned short f2bf(float f) {
  unsigned u = __float_as_uint(f);
  return (unsigned short)((u + 0x7fffu + ((u >> 16) & 1u)) >> 16);
}

// ---------------- prep: swizzled bf16 weights + bias ----------------
// W'[feat][k]: feat<48 -> theta_w row; feat>=48 -> (phi_w - theta_w) row.
// Stored in MFMA B-frag order: wcs[((ntile*2+kstep)*64 + lane)*8 + j] =
// W'[ntile*16 + (lane&15)][kstep*32 + (lane>>4)*8 + j], zero-padded K 48->64.
// Each lane's b-frag is then one contiguous 16 B load.
__global__ __launch_bounds__(256) void prep(
    const float* __restrict__ tw, const float* __restrict__ tb,
    const float* __restrict__ pw, const float* __restrict__ pb,
    unsigned short* __restrict__ wcs, float* __restrict__ bias) {
  int i = blockIdx.x * 256 + threadIdx.x;
  if (i < 6144) {
    int j = i & 7;
    int fragpos = i >> 3;
    int lane = fragpos & 63;
    int frag = fragpos >> 6;
    int kstep = frag & 1;
    int ntile = frag >> 1;
    int feat = ntile * 16 + (lane & 15);
    int k = kstep * 32 + (lane >> 4) * 8 + j;
    float v = 0.f;
    if (k < DIN) {
      v = (feat < DOUT) ? tw[feat * DIN + k]
                        : pw[(feat - DOUT) * DIN + k] - tw[(feat - DOUT) * DIN + k];
    }
    wcs[i] = f2bf(v);
  } else if (i < 6144 + 96) {
    int f = i - 6144;
    bias[f] = (f < DOUT) ? tb[f] : pb[f - DOUT];
  }
}

// ---------------- per-node linear transforms via MFMA ----------------
// out_tile[16 nodes][96 feats] = h_tile @ W'^T + bias, one wave per tile.
// feats 0..47 -> A (fp32, d_out; bucket_max epilogue adds max-term),
// feats 48..95 -> B (bf16 workspace for the gather).
// Layouts per learn_hip m89/m91: A-frag A[m=lane&15][k=quad*8+j];
// B-frag B[n=lane&15][k=quad*8+j]; D: col(n)=lane&15, row(m)=quad*4+reg.
// Round-10 lesson: the VALU version was issue/latency-bound at 1.5 blocks/CU;
// MFMA cuts per-node instruction count ~100x and the 1563-block grid fills
// the machine.
__global__ __launch_bounds__(256) void node_transform(
    const float* __restrict__ h, const unsigned short* __restrict__ wcs,
    const float* __restrict__ bias, float* __restrict__ A,
    unsigned short* __restrict__ Bh, int n_nodes) {
  int t = threadIdx.x;
  int wave = t >> 6, lane = t & 63;
  int quad = lane >> 4, nl = lane & 15;
  int vb = blockIdx.x * 64 + wave * 16;
  int vload = vb + nl;

  // A-frags for kstep0 (k=0..31) and kstep1 (k=32..63; k>=48 zero-padded)
  s16x8 a0 = {0, 0, 0, 0, 0, 0, 0, 0};
  s16x8 a1 = {0, 0, 0, 0, 0, 0, 0, 0};
  if (vload < n_nodes) {
    const float* hp = h + (size_t)vload * DIN;
    float4 x = *reinterpret_cast<const float4*>(hp + quad * 8);
    float4 y = *reinterpret_cast<const float4*>(hp + quad * 8 + 4);
    a0[0] = (short)f2bf(x.x); a0[1] = (short)f2bf(x.y);
    a0[2] = (short)f2bf(x.z); a0[3] = (short)f2bf(x.w);
    a0[4] = (short)f2bf(y.x); a0[5] = (short)f2bf(y.y);
    a0[6] = (short)f2bf(y.z); a0[7] = (short)f2bf(y.w);
    if (quad < 2) {  // k = 32 + quad*8 + j < 48 only for quads 0,1
      float4 z = *reinterpret_cast<const float4*>(hp + 32 + quad * 8);
      float4 u = *reinterpret_cast<const float4*>(hp + 32 + quad * 8 + 4);
      a1[0] = (short)f2bf(z.x); a1[1] = (short)f2bf(z.y);
      a1[2] = (short)f2bf(z.z); a1[3] = (short)f2bf(z.w);
      a1[4] = (short)f2bf(u.x); a1[5] = (short)f2bf(u.y);
      a1[6] = (short)f2bf(u.z); a1[7] = (short)f2bf(u.w);
    }
  }

  const s16x8* wf = reinterpret_cast<const s16x8*>(wcs);
  f32x4v acc[6];
#pragma unroll
  for (int nt = 0; nt < 6; ++nt) {
    float bv = bias[nt * 16 + nl];  // col n = lane&15: same bias for all rows
    acc[nt] = (f32x4v){bv, bv, bv, bv};
  }
#pragma unroll
  for (int nt = 0; nt < 6; ++nt) {
    s16x8 b0 = wf[(nt * 2 + 0) * 64 + lane];  // coalesced, L2-hot (12 KB total)
    s16x8 b1 = wf[(nt * 2 + 1) * 64 + lane];
    acc[nt] = __builtin_amdgcn_mfma_f32_16x16x32_bf16(a0, b0, acc[nt], 0, 0, 0);
    acc[nt] = __builtin_amdgcn_mfma_f32_16x16x32_bf16(a1, b1, acc[nt], 0, 0, 0);
  }

  // D store: row m=quad*4+reg, col n=nl. Per (quad,reg) 16 lanes write 64 B
  // contiguous fp32 (A) / 32 B bf16 (Bh); wave covers the full 16x96 tile so
  // all touched lines are fully written (no amplification).
#pragma unroll
  for (int reg = 0; reg < 4; ++reg) {
    int v = vb + quad * 4 + reg;
    if (v < n_nodes) {
#pragma unroll
      for (int nt = 0; nt < 3; ++nt)
        A[(size_t)v * DOUT + nt * 16 + nl] = acc[nt][reg];
#pragma unroll
      for (int nt = 3; nt < 6; ++nt)
        Bh[(size_t)v * DOUT + (nt - 3) * 16 + nl] = f2bf(acc[nt][reg]);
    }
  }
}

// ---------------- bin edges: per-block LDS counting sort ----------------
// Deterministic: zero global atomics, 3 barriers, exact sizes. Records land
// bucket-grouped in the block's private 12.5 KB window; scattered stores are
// temporally clustered within one window -> L2 write-combines to full lines.
__global__ __launch_bounds__(256) void bin_edges(
    const int* __restrict__ src, const int* __restrict__ dst,
    unsigned* __restrict__ ebuf, unsigned* __restrict__ soffs,
    int n_edges, int nbucket, int epb) {
  __shared__ unsigned rec[EPB_MAX];          // 12.5 KB
  __shared__ unsigned short rbkt[EPB_MAX];   // 6.3 KB
  __shared__ unsigned cnt[NB_MAX];           // counts -> offsets -> cursors
  __shared__ unsigned part[256];
  int t = threadIdx.x, r = blockIdx.x;
  for (int b = t; b < nbucket; b += 256) cnt[b] = 0;
  __syncthreads();

  int start = r * epb;
  int nrec = n_edges - start;
  if (nrec > epb) nrec = epb;
  if (nrec < 0) nrec = 0;

  for (int k = t; k < nrec; k += 256) {
    int s = src[start + k], d = dst[start + k];
    int b = d >> 7;
    rec[k] = ((unsigned)(d & (NPB - 1)) << 17) | (unsigned)s;
    rbkt[k] = (unsigned short)b;
    atomicAdd(&cnt[b], 1u);
  }
  __syncthreads();

  int per = (nbucket + 255) / 256;  // 4
  unsigned local[8];
  unsigned s = 0;
#pragma unroll 4
  for (int i = 0; i < per; ++i) {
    int idx = t * per + i;
    local[i] = (idx < nbucket) ? cnt[idx] : 0u;
    s += local[i];
  }
  part[t] = s;
  __syncthreads();
  for (int off = 1; off < 256; off <<= 1) {
    unsigned v = (t >= off) ? part[t - off] : 0u;
    __syncthreads();
    part[t] += v;
    __syncthreads();
  }
  unsigned run = part[t] - s;
  unsigned* orow = soffs + (size_t)r * (nbucket + 1);
#pragma unroll 4
  for (int i = 0; i < per; ++i) {
    int idx = t * per + i;
    if (idx < nbucket) {
      cnt[idx] = run;
      orow[idx] = run;
      run += local[i];
    }
  }
  if (t == 0) orow[nbucket] = (unsigned)nrec;
  __syncthreads();

  for (int k = t; k < nrec; k += 256) {
    unsigned p = atomicAdd(&cnt[rbkt[k]], 1u);
    ebuf[(size_t)r * epb + p] = rec[k];
  }
}

// ---------------- per-bucket scatter-max in LDS ----------------
#define BM_THREADS 512
#define BM_GROUPS 42
__global__ __launch_bounds__(BM_THREADS) void bucket_max(
    const unsigned* __restrict__ ebuf, const unsigned* __restrict__ soffs,
    const unsigned short* __restrict__ Bh, float* __restrict__ out,
    int n_nodes, int nbucket, int epb) {
  __shared__ unsigned keys[NPB * DOUT];   // 24.6 KB
  __shared__ unsigned segs[BIN_BLOCKS];   // (start | end<<16), both < 3136
  int t = threadIdx.x;
  int bkt = blockIdx.x;
#pragma unroll
  for (int i = t; i < NPB * DOUT; i += BM_THREADS) keys[i] = INIT_KEY;
  if (t < BIN_BLOCKS) {
    const unsigned* row = soffs + (size_t)t * (nbucket + 1);
    unsigned a = row[bkt], b = row[bkt + 1];
    segs[t] = a | (b << 16);
  }
  __syncthreads();

  int g = t / 12;
  int c = t % 12;
  if (g < BM_GROUPS) {
    for (int r = g; r < BIN_BLOCKS; r += BM_GROUPS) {
      unsigned se = segs[r];
      unsigned j0 = se & 0xffffu, j1 = se >> 16;
      const unsigned* ep = ebuf + (size_t)r * epb;
      unsigned j = j0;
      for (; j + 1 < j1; j += 2) {
        unsigned v0 = ep[j], v1 = ep[j + 1];
        uint2 b0 = *reinterpret_cast<const uint2*>(Bh + (size_t)(v0 & 0x1FFFF) * DOUT + c * 4);
        uint2 b1 = *reinterpret_cast<const uint2*>(Bh + (size_t)(v1 & 0x1FFFF) * DOUT + c * 4);
        unsigned* k0 = &keys[(v0 >> 17) * DOUT + c * 4];
        unsigned* k1 = &keys[(v1 >> 17) * DOUT + c * 4];
        atomicMax(&k0[0], bfkey(b0.x & 0xffffu)); atomicMax(&k0[1], bfkey(b0.x >> 16));
        atomicMax(&k0[2], bfkey(b0.y & 0xffffu)); atomicMax(&k0[3], bfkey(b0.y >> 16));
        atomicMax(&k1[0], bfkey(b1.x & 0xffffu)); atomicMax(&k1[1], bfkey(b1.x >> 16));
        atomicMax(&k1[2], bfkey(b1.y & 0xffffu)); atomicMax(&k1[3], bfkey(b1.y >> 16));
      }
      if (j < j1) {
        unsigned v0 = ep[j];
        uint2 b0 = *reinterpret_cast<const uint2*>(Bh + (size_t)(v0 & 0x1FFFF) * DOUT + c * 4);
        unsigned* k0 = &keys[(v0 >> 17) * DOUT + c * 4];
        atomicMax(&k0[0], bfkey(b0.x & 0xffffu)); atomicMax(&k0[1], bfkey(b0.x >> 16));
        atomicMax(&k0[2], bfkey(b0.y & 0xffffu)); atomicMax(&k0[3], bfkey(b0.y >> 16));
      }
    }
  }
  __syncthreads();

  int node0 = bkt * NPB;
  for (int i = t; i < NPB * (DOUT / 4); i += BM_THREADS) {
    int n = i / (DOUT / 4), cc = i % (DOUT / 4);
    int v = node0 + n;
    if (v < n_nodes) {
      unsigned* kp = &keys[n * DOUT + 4 * cc];
      unsigned k0 = kp[0], k1 = kp[1], k2 = kp[2], k3 = kp[3];
      float4* op = reinterpret_cast<float4*>(out + (size_t)v * DOUT + 4 * cc);
      float4 a = *op;
      float4 r;
      r.x = (k0 == INIT_KEY) ? 0.f : a.x + funkey(k0);
      r.y = (k1 == INIT_KEY) ? 0.f : a.y + funkey(k1);
      r.z = (k2 == INIT_KEY) ? 0.f : a.z + funkey(k2);
      r.w = (k3 == INIT_KEY) ? 0.f : a.w + funkey(k3);
      *op = r;
    }
  }
}

extern "C" void kernel_launch(void* const* d_in, const int* in_sizes, int n_in,
                              void* d_out, int out_size, void* d_ws, size_t ws_size,
                              hipStream_t stream) {
  const float* h  = (const float*)d_in[0];
  const float* tw = (const float*)d_in[1];
  const float* tb = (const float*)d_in[2];
  const float* pw = (const float*)d_in[3];
  const float* pb = (const float*)d_in[4];
  const int* src  = (const int*)d_in[5];
  const int* dst  = (const int*)d_in[6];
  int n_nodes = in_sizes[0] / DIN;
  int n_edges = in_sizes[5];
  int nbucket = (n_nodes + NPB - 1) / NPB;             // 782
  int epb = (n_edges + BIN_BLOCKS - 1) / BIN_BLOCKS;   // 3125

  // workspace layout
  unsigned short* Bh  = (unsigned short*)d_ws;                       // 9.6 MB
  unsigned* ebuf      = (unsigned*)(Bh + (size_t)n_nodes * DOUT);    // 6.4 MB
  unsigned* soffs     = ebuf + (size_t)BIN_BLOCKS * epb;             // 1.6 MB
  unsigned short* wcs = (unsigned short*)(soffs + (size_t)BIN_BLOCKS * (nbucket + 1));  // 12.3 KB
  float* bias         = (float*)(wcs + 6144);                        // 384 B
  float* A            = (float*)d_out;

  int nt_blocks = (n_nodes + 63) / 64;  // 1563

  prep<<<25, 256, 0, stream>>>(tw, tb, pw, pb, wcs, bias);
  node_transform<<<nt_blocks, 256, 0, stream>>>(h, wcs, bias, A, Bh, n_nodes);
  bin_edges<<<BIN_BLOCKS, 256, 0, stream>>>(src, dst, ebuf, soffs, n_edges, nbucket, epb);
  bucket_max<<<nbucket, BM_THREADS, 0, stream>>>(ebuf, soffs, Bh, A, n_nodes, nbucket, epb);
}